// Round 24
// baseline (525.800 us; speedup 1.0000x reference)
//
#include <hip/hip_runtime.h>
#include <cstdint>
#include <cstddef>

#define N_TOK 8192
#define DM 1024
#define DFF 4096
#define NE 8
#define PAD 256
#define CAP (N_TOK * 2 + NE * PAD)  // 18432
#define NT1 ((DFF / 128) * (CAP / 256))  // 2304 gemm1 tiles

typedef __attribute__((ext_vector_type(8))) short bf16x8;
typedef __attribute__((ext_vector_type(8))) unsigned short u16x8;
typedef __attribute__((ext_vector_type(4))) float f32x4;

__device__ __forceinline__ unsigned short f2bf(float f) {
  union { float f; unsigned u; } v; v.f = f;
  unsigned r = v.u + 0x7FFFu + ((v.u >> 16) & 1u);
  return (unsigned short)(r >> 16);
}
__device__ __forceinline__ float bf2f(unsigned short h) {
  union { unsigned u; float f; } v; v.u = ((unsigned)h) << 16;
  return v.f;
}

__device__ __forceinline__ void async16(unsigned short* l, const unsigned short* g) {
  __builtin_amdgcn_global_load_lds(
      (const __attribute__((address_space(1))) unsigned int*)g,
      (__attribute__((address_space(3))) unsigned int*)l, 16, 0, 0);
}

// ---------------- router: two-level ranks + inline offsets (R21/R22) ---------
__global__ __launch_bounds__(256) void router_kernel(
    const float* __restrict__ x, const float* __restrict__ Wr,
    unsigned* __restrict__ counts, float* __restrict__ Psum,
    int* __restrict__ tok_e, float* __restrict__ tok_g, int* __restrict__ tok_ls,
    unsigned* __restrict__ done, int* __restrict__ offs, float* __restrict__ aux_out) {
  __shared__ float ps[NE];
  __shared__ unsigned lcnt[NE];
  __shared__ unsigned base[NE];
  const int bid = blockIdx.x;
  const int tid = threadIdx.x;
  if (tid < NE) { ps[tid] = 0.f; lcnt[tid] = 0u; }
  __syncthreads();
  const int lane = tid & 63, wid = tid >> 6;
  int li0[4], li1[4];
  unsigned lr0[4], lr1[4];
  float lg0[4], lg1[4];
#pragma unroll
  for (int u = 0; u < 4; ++u) {
    const int t = bid * 16 + wid * 4 + u;
    float a[NE];
#pragma unroll
    for (int e = 0; e < NE; ++e) a[e] = 0.f;
#pragma unroll
    for (int i = 0; i < 4; ++i) {
      const int d0 = i * 256 + lane * 4;
      const float4 v = *(const float4*)&x[(size_t)t * DM + d0];
      const float vv[4] = {v.x, v.y, v.z, v.w};
#pragma unroll
      for (int j = 0; j < 4; ++j) {
        const float* wr = &Wr[(size_t)(d0 + j) * NE];
#pragma unroll
        for (int e = 0; e < NE; ++e) a[e] = fmaf(vv[j], wr[e], a[e]);
      }
    }
#pragma unroll
    for (int e = 0; e < NE; ++e)
      for (int s = 32; s > 0; s >>= 1) a[e] += __shfl_xor(a[e], s);
    float mx = a[0];
#pragma unroll
    for (int e = 1; e < NE; ++e) mx = fmaxf(mx, a[e]);
    float p[NE], s = 0.f;
#pragma unroll
    for (int e = 0; e < NE; ++e) { p[e] = expf(a[e] - mx); s += p[e]; }
    float q[NE];
#pragma unroll
    for (int e = 0; e < NE; ++e) q[e] = p[e] / s;
    int i0 = 0; float b0 = q[0];
#pragma unroll
    for (int e = 1; e < NE; ++e) if (q[e] > b0) { b0 = q[e]; i0 = e; }
    int i1 = -1; float b1v = -1.f;
#pragma unroll
    for (int e = 0; e < NE; ++e) if (e != i0 && q[e] > b1v) { b1v = q[e]; i1 = e; }
    const float gs = q[i0] + q[i1];
    li0[u] = i0; li1[u] = i1;
    lg0[u] = q[i0] / gs; lg1[u] = q[i1] / gs;
    if (lane == 0) {
#pragma unroll
      for (int e = 0; e < NE; ++e) atomicAdd(&ps[e], q[e]);
      lr0[u] = atomicAdd(&lcnt[i0], 1u);
      lr1[u] = atomicAdd(&lcnt[i1], 1u);
    }
  }
  __syncthreads();
  if (tid < NE) {
    base[tid] = atomicAdd(&counts[tid], lcnt[tid]);
    atomicAdd(&Psum[tid], ps[tid]);
  }
  __syncthreads();
  if (lane == 0) {
#pragma unroll
    for (int u = 0; u < 4; ++u) {
      const int t = bid * 16 + wid * 4 + u;
      tok_e[2 * t] = li0[u]; tok_e[2 * t + 1] = li1[u];
      tok_g[2 * t] = lg0[u]; tok_g[2 * t + 1] = lg1[u];
      tok_ls[2 * t] = (int)(base[li0[u]] + lr0[u]);
      tok_ls[2 * t + 1] = (int)(base[li1[u]] + lr1[u]);
    }
  }
  __syncthreads();
  if (tid == 0) {
    __threadfence();
    const unsigned d = atomicAdd(done, 1u);
    if (d == 511u) {
      int o = 0; float aux = 0.f;
#pragma unroll
      for (int e = 0; e < NE; ++e) {
        const unsigned c = atomicAdd(&counts[e], 0u);   // atomic read (G16)
        const float pe = atomicAdd(&Psum[e], 0.f);
        offs[e] = o;
        o += (int)((c + (PAD - 1u)) / PAD) * PAD;
        aux += ((float)c / (float)N_TOK) * (pe / (float)N_TOK);
      }
      offs[NE] = o;
      aux_out[0] = 0.01f * (float)NE * aux;
    }
  }
}

// ------ fused: gather (blocks 0..8191) || W1 transpose (blocks 8192..16383) --
// R24: gather needs only router outputs; W1T needs only W1 -- independent, so
// they co-run in one dispatch (~max(18,32)us vs ~50 serial). GEMM1 needs both
// Xg and W1T, complete at this dispatch's end (stream order).
__global__ __launch_bounds__(256) void gather_w1t(
    const float* __restrict__ x, const int* __restrict__ tok_e,
    const int* __restrict__ tok_ls, const int* __restrict__ offs,
    int* __restrict__ tok_slot, unsigned short* __restrict__ Xg,
    const float* __restrict__ W1, unsigned short* __restrict__ W1T) {
  const int bid = blockIdx.x;
  const int tid = threadIdx.x;

  if (bid >= N_TOK) {
    // ---- W1 transpose+cvt: (DM x DFF) -> (DFF x DM), 1024 tiles/expert
    __shared__ float tile[64][65];
    const int b = bid - N_TOK;
    const int z = b >> 10;
    const float* I = W1 + (size_t)z * DM * DFF;
    unsigned short* O = W1T + (size_t)z * DM * DFF;
    const int bt = b & 1023;
    const int bx = bt & 63, by = bt >> 6;  // nbx = DFF/64 = 64
    const int r0 = by * 64, c0 = bx * 64;
    const int q = tid & 15, p = tid >> 4;
#pragma unroll
    for (int i = 0; i < 4; ++i) {
      const int r = i * 16 + p;
      const float4 v = *(const float4*)&I[(size_t)(r0 + r) * DFF + c0 + q * 4];
      tile[r][q * 4 + 0] = v.x; tile[r][q * 4 + 1] = v.y;
      tile[r][q * 4 + 2] = v.z; tile[r][q * 4 + 3] = v.w;
    }
    __syncthreads();
#pragma unroll
    for (int i = 0; i < 4; ++i) {
      const int cc = i * 16 + p;
      ushort4 h;
      h.x = f2bf(tile[q * 4 + 0][cc]);
      h.y = f2bf(tile[q * 4 + 1][cc]);
      h.z = f2bf(tile[q * 4 + 2][cc]);
      h.w = f2bf(tile[q * 4 + 3][cc]);
      *(ushort4*)&O[(size_t)(c0 + cc) * DM + r0 + q * 4] = h;
    }
    return;
  }

  // ---- gather: token bid -> 2 slots
  const int t = bid;
  __shared__ int ss[2];
  if (tid < 2) {
    const int k = tid;
    const int e = tok_e[2 * t + k];
    const int sl = offs[e] + tok_ls[2 * t + k];
    ss[k] = sl;
    tok_slot[2 * t + k] = sl;
  }
  __syncthreads();
  const int i = tid;
  const float4 v = ((const float4*)x)[(size_t)t * 256 + i];
  ushort4 h;
  h.x = f2bf(v.x); h.y = f2bf(v.y); h.z = f2bf(v.z); h.w = f2bf(v.w);
  ((ushort4*)Xg)[(size_t)ss[0] * 256 + i] = h;
  ((ushort4*)Xg)[(size_t)ss[1] * 256 + i] = h;
}

// ---------------- shape-templated GEMM, BK=32, ring-3, 2 blocks/CU -----------
// Inner loop FROZEN at R12 best (208us/GEMM, 31% MfmaUtil, 0 conflicts).
// BMODE 0 flat grid: blocks >= NT1 run the W2->W2T transpose hidden under
// GEMM1 (R23-proven, +2us on the dispatch, -32us serial). Blocks < NT1:
// tn = f%32, gr = f/32. BMODE 1: split-K=2, XCD-banded flat 1152.
// 16B chunks XOR-swizzled ((row>>1)&3) both sides. Per K-tile: 8 ds_read +
// 16 MFMA + 3 stage loads + vmcnt(3) + 1 barrier. tanh-GELU epilogue.
template <int BMODE, bool GELU, typename CT>
__global__ __launch_bounds__(512, 4) void gemmk(
    const unsigned short* __restrict__ Ag, const unsigned short* __restrict__ Bt,
    const float* __restrict__ bias, CT* __restrict__ Cout,
    const int* __restrict__ offs, const int K, const int Nn,
    const size_t c_split_stride,
    const float* __restrict__ TW_in, unsigned short* __restrict__ TW_out) {
  constexpr int BM = (BMODE == 0) ? 256 : 128;
  constexpr int BN = (BMODE == 0) ? 128 : 256;
  constexpr int WN = BN / 64;                  // waves along N
  constexpr int AREG = BM * 32;                // shorts per A ring entry
  constexpr int BREG = BN * 32;                // shorts per B ring entry
  constexpr int SPLIT = (BMODE == 0) ? 1 : 2;

  extern __shared__ unsigned short lds[];
  const int tid = threadIdx.x;

  int tn, gr, ks;
  if (BMODE == 0) {
    const int flat = (int)blockIdx.x;
    if (flat >= NT1) {
      // ---- W2 transpose+cvt (DFF x DM) -> (DM x DFF), 512 threads
      float* tile = (float*)lds;  // [64][65]
      const int b = flat - NT1;
      const int z = b >> 10;
      const float* I = TW_in + (size_t)z * DM * DFF;
      unsigned short* O = TW_out + (size_t)z * DM * DFF;
      const int bt = b & 1023;
      const int bx = bt & 15, by = bt >> 4;  // nbx = DM/64 = 16
      const int r0 = by * 64, c0 = bx * 64;
      const int q = tid & 15, p = tid >> 4;  // p 0..31
#pragma unroll
      for (int i = 0; i < 2; ++i) {
        const int r = i * 32 + p;
        const float4 v = *(const float4*)&I[(size_t)(r0 + r) * DM + c0 + q * 4];
        tile[r * 65 + q * 4 + 0] = v.x; tile[r * 65 + q * 4 + 1] = v.y;
        tile[r * 65 + q * 4 + 2] = v.z; tile[r * 65 + q * 4 + 3] = v.w;
      }
      __syncthreads();
#pragma unroll
      for (int i = 0; i < 2; ++i) {
        const int cc = i * 32 + p;
        ushort4 h;
        h.x = f2bf(tile[(q * 4 + 0) * 65 + cc]);
        h.y = f2bf(tile[(q * 4 + 1) * 65 + cc]);
        h.z = f2bf(tile[(q * 4 + 2) * 65 + cc]);
        h.w = f2bf(tile[(q * 4 + 3) * 65 + cc]);
        *(ushort4*)&O[(size_t)(c0 + cc) * DFF + r0 + q * 4] = h;
      }
      return;
    }
    tn = flat & 31; gr = flat >> 5; ks = 0;   // tn fast
  } else {
    const int flat = (int)blockIdx.x;         // XCD-banded flat
    const int xr = flat & 7;
    const int rest = flat >> 3;
    tn = rest & 3; ks = (rest >> 2) & 1; gr = ((rest >> 3) << 3) + xr;
  }

  const int grow = gr * BM;
  if (grow >= offs[NE]) return;
  int e = 0;
#pragma unroll
  for (int k = 1; k < NE; ++k) if (offs[k] <= grow) e = k;
  const int kext = K / SPLIT;
  const int nt = kext >> 5;  // K-tiles of 32

  const unsigned short* A = Ag + (size_t)grow * K + (size_t)ks * kext;
  const unsigned short* B = Bt + ((size_t)e * Nn + (size_t)tn * BN) * K + (size_t)ks * kext;
  const float* bp = (ks == 0) ? bias : nullptr;
  CT* Cw = Cout + (size_t)ks * c_split_stride;

  unsigned short* LA = lds;                  // 3 x AREG
  unsigned short* LB = lds + 3 * AREG;       // 3 x BREG

  const int lane = tid & 63;
  const int wid = tid >> 6;
  const int wm = wid / WN;
  const int wn = wid % WN;
  const int arow = lane & 15;
  const int kc = lane >> 4;   // 16B chunk 0..3 within 32-short row

  // LDS read addressing: swizzled chunk (kc ^ ((row>>1)&3)); row%8 == arow%8.
  const int sc = ((kc ^ ((arow >> 1) & 3)) << 3);
  const int aBase = (wm * 64 + arow) * 32 + sc;   // + mf*512
  const int bBase = (wn * 64 + arow) * 32 + sc;   // + nf*512

  // stage addressing: chunk c = call*512 + tid; r = c>>2; src chunk
  // (tid&3)^((r>>1)&3) = (tid&3)^((tid>>3)&3) (call adds 128 rows = 0 mod 8).
  const int swzs = (((tid & 3) ^ ((tid >> 3) & 3)) << 3);
  const unsigned short* sA = A + (size_t)(tid >> 2) * K + swzs;
  const unsigned short* sB = B + (size_t)(tid >> 2) * K + swzs;
  const size_t r128 = (size_t)128 * K;
  const size_t dstw = (size_t)wid * 512;  // shorts; lane*16B added by HW

  auto stgA = [&](int db, size_t kt) {
    async16(LA + db * AREG + dstw, sA + kt);
    if constexpr (BMODE == 0) async16(LA + db * AREG + 4096 + dstw, sA + r128 + kt);
  };
  auto stgB = [&](int db, size_t kt) {
    async16(LB + db * BREG + dstw, sB + kt);
    if constexpr (BMODE == 1) async16(LB + db * BREG + 4096 + dstw, sB + r128 + kt);
  };

  f32x4 acc[4][4];
#pragma unroll
  for (int m = 0; m < 4; ++m)
#pragma unroll
    for (int n = 0; n < 4; ++n) acc[m][n] = (f32x4){0.f, 0.f, 0.f, 0.f};

  // prologue: stage T0 -> buf0, T1 -> buf1; wait T0 (counted), barrier.
  stgA(0, 0); stgB(0, 0);
  stgA(1, 32); stgB(1, 32);
  asm volatile("s_waitcnt vmcnt(3)" ::: "memory");
  asm volatile("s_barrier" ::: "memory");

  int d0 = 0;
  for (int T = 0; T < nt; ++T) {
    const int d2 = (d0 >= 1) ? d0 - 1 : d0 + 2;  // (d0+2)%3
    const size_t kt2 = (size_t)((T + 2 < nt) ? T + 2 : 0) << 5;
    const int la = d0 * AREG, lb = d0 * BREG;

    bf16x8 afr[4], bfr[4];
#pragma unroll
    for (int mf = 0; mf < 4; ++mf) afr[mf] = *(const bf16x8*)&LA[la + aBase + mf * 512];
#pragma unroll
    for (int nf = 0; nf < 4; ++nf) bfr[nf] = *(const bf16x8*)&LB[lb + bBase + nf * 512];

    stgA(d2, kt2);
    stgB(d2, kt2);

    __builtin_amdgcn_s_setprio(1);
#pragma unroll
    for (int m = 0; m < 4; ++m)
#pragma unroll
      for (int n = 0; n < 4; ++n)
        acc[m][n] = __builtin_amdgcn_mfma_f32_16x16x32_bf16(afr[m], bfr[n], acc[m][n], 0, 0, 0);
    __builtin_amdgcn_s_setprio(0);

    asm volatile("s_waitcnt vmcnt(3)" ::: "memory");
    asm volatile("s_barrier" ::: "memory");
    d0 = (d0 == 2) ? 0 : d0 + 1;
  }
  asm volatile("s_waitcnt vmcnt(0)" ::: "memory");

  // epilogue: n innermost -> each output line completed back-to-back (no RMW).
  const int rl = (lane >> 4) * 4;
  const int cl = lane & 15;
  float bv[4];
#pragma unroll
  for (int n = 0; n < 4; ++n) {
    const int col = tn * BN + wn * 64 + n * 16 + cl;
    bv[n] = bp ? bp[(size_t)e * Nn + col] : 0.f;
  }
#pragma unroll
  for (int m = 0; m < 4; ++m) {
    const int row = grow + wm * 64 + m * 16 + rl;
#pragma unroll
    for (int jj = 0; jj < 4; ++jj) {
      CT* rowp = Cw + (size_t)(row + jj) * Nn + tn * BN + wn * 64 + cl;
#pragma unroll
      for (int n = 0; n < 4; ++n) {
        float v = acc[m][n][jj] + bv[n];
        if (GELU) {
          // tanh-approx GELU, sigmoid form (inf-safe)
          const float w = -1.5957691216057308f * (v + 0.044715f * v * v * v);
          v = v / (1.f + __expf(w));
        }
        if constexpr (sizeof(CT) == 2) { rowp[n * 16] = (CT)f2bf(v); } else { rowp[n * 16] = (CT)v; }
      }
    }
  }
}

// ---------------- combine: out[t] = g0*(Ya+Yb)[s0] + g1*(Ya+Yb)[s1] ----------
__global__ __launch_bounds__(128) void combine_kernel(
    const unsigned short* __restrict__ Ya, const unsigned short* __restrict__ Yb,
    const int* __restrict__ tok_slot, const float* __restrict__ tok_g,
    float* __restrict__ out) {
  const int t = blockIdx.x;
  const int i = threadIdx.x;
  const int s0 = tok_slot[2 * t], s1 = tok_slot[2 * t + 1];
  const float g0 = tok_g[2 * t], g1 = tok_g[2 * t + 1];
  const u16x8 a0 = ((const u16x8*)Ya)[(size_t)s0 * 128 + i];
  const u16x8 b0 = ((const u16x8*)Yb)[(size_t)s0 * 128 + i];
  const u16x8 a1 = ((const u16x8*)Ya)[(size_t)s1 * 128 + i];
  const u16x8 b1 = ((const u16x8*)Yb)[(size_t)s1 * 128 + i];
  float r[8];
#pragma unroll
  for (int j = 0; j < 8; ++j)
    r[j] = g0 * (bf2f(a0[j]) + bf2f(b0[j])) + g1 * (bf2f(a1[j]) + bf2f(b1[j]));
  float4* op = (float4*)&out[(size_t)t * DM + i * 8];
  op[0] = (float4){r[0], r[1], r[2], r[3]};
  op[1] = (float4){r[4], r[5], r[6], r[7]};
}

extern "C" void kernel_launch(void* const* d_in, const int* in_sizes, int n_in,
                              void* d_out, int out_size, void* d_ws, size_t ws_size,
                              hipStream_t stream) {
  const float* x = (const float*)d_in[0];
  const float* Wr = (const float*)d_in[1];
  const float* W1 = (const float*)d_in[2];
  const float* b1 = (const float*)d_in[3];
  const float* W2 = (const float*)d_in[4];
  const float* b2 = (const float*)d_in[5];
  float* out = (float*)d_out;

  char* w = (char*)d_ws;
  size_t ob = 0;
  auto take = [&](size_t nbytes) -> void* {
    void* p = w + ob;
    ob = (ob + nbytes + 255) & ~(size_t)255;
    return p;
  };
  // Overlap: {W1T,Xg} (dead after GEMM1) share a region with {Ya,Yb} (bf16)
  unsigned short* W2T = (unsigned short*)take((size_t)NE * DM * DFF * 2);   // 64MB
  unsigned short* H = (unsigned short*)take((size_t)CAP * DFF * 2);         // 151MB
  char* R = (char*)take((size_t)NE * DFF * DM * 2 + (size_t)CAP * DM * 2);  // 100MB
  unsigned short* W1T = (unsigned short*)R;                                 // 64MB
  unsigned short* Xg = (unsigned short*)(R + (size_t)NE * DFF * DM * 2);    // 36MB
  unsigned short* Ya = (unsigned short*)R;                                  // 36MB
  unsigned short* Yb = (unsigned short*)(R + (size_t)CAP * DM * 2);         // 36MB
  char* cz = (char*)take(128);  // counts(32) + Psum(32) + done(4), memset-zeroed
  unsigned* counts = (unsigned*)cz;
  float* Psum = (float*)(cz + 32);
  unsigned* done = (unsigned*)(cz + 64);
  int* offs = (int*)take(16 * 4);
  int* tok_e = (int*)take(2 * N_TOK * 4);
  float* tok_g = (float*)take(2 * N_TOK * 4);
  int* tok_ls = (int*)take(2 * N_TOK * 4);
  int* tok_slot = (int*)take(2 * N_TOK * 4);
  (void)ws_size; (void)in_sizes; (void)n_in; (void)out_size;

  hipFuncSetAttribute(reinterpret_cast<const void*>(&gemmk<0, true, unsigned short>),
                      hipFuncAttributeMaxDynamicSharedMemorySize, 73728);
  hipFuncSetAttribute(reinterpret_cast<const void*>(&gemmk<1, false, unsigned short>),
                      hipFuncAttributeMaxDynamicSharedMemorySize, 73728);

  hipMemsetAsync(cz, 0, 128, stream);
  // router only (~15-20us) with inline offsets via done-counter
  router_kernel<<<512, 256, 0, stream>>>(
      x, Wr, counts, Psum, tok_e, tok_g, tok_ls,
      done, offs, out + (size_t)N_TOK * DM);
  // fused gather || W1 transpose (independent; both needed by GEMM1)
  gather_w1t<<<N_TOK + 8 * 1024, 256, 0, stream>>>(
      x, tok_e, tok_ls, offs, tok_slot, Xg, W1, W1T);
  // GEMM1 (BM=256,BN=128) + fused W2 transpose (blocks >= NT1, hidden tail)
  gemmk<0, true, unsigned short><<<dim3(NT1 + 8 * 1024), 512, 73728, stream>>>(
      Xg, W1T, b1, H, offs, DM, DFF, 0, W2, W2T);
  // GEMM2 (BM=128,BN=256, split-K=2): XCD-banded flat 1152; halves write Ya/Yb
  gemmk<1, false, unsigned short><<<dim3((CAP / 128) * 8), 512, 73728, stream>>>(
      H, W2T, b2, Ya, offs, DFF, DM, (size_t)CAP * DM, nullptr, nullptr);
  combine_kernel<<<N_TOK, 128, 0, stream>>>(Ya, Yb, tok_slot, tok_g, out);
}

// Round 25
// 509.571 us; speedup vs baseline: 1.0318x; 1.0318x over previous
//
#include <hip/hip_runtime.h>
#include <cstdint>
#include <cstddef>

#define N_TOK 8192
#define DM 1024
#define DFF 4096
#define NE 8
#define PAD 256
#define CAP (N_TOK * 2 + NE * PAD)  // 18432
#define NT1 ((DFF / 128) * (CAP / 256))  // 2304 gemm1 tiles

typedef __attribute__((ext_vector_type(8))) short bf16x8;
typedef __attribute__((ext_vector_type(8))) unsigned short u16x8;
typedef __attribute__((ext_vector_type(4))) float f32x4;

__device__ __forceinline__ unsigned short f2bf(float f) {
  union { float f; unsigned u; } v; v.f = f;
  unsigned r = v.u + 0x7FFFu + ((v.u >> 16) & 1u);
  return (unsigned short)(r >> 16);
}
__device__ __forceinline__ float bf2f(unsigned short h) {
  union { unsigned u; float f; } v; v.u = ((unsigned)h) << 16;
  return v.f;
}

__device__ __forceinline__ void async16(unsigned short* l, const unsigned short* g) {
  __builtin_amdgcn_global_load_lds(
      (const __attribute__((address_space(1))) unsigned int*)g,
      (__attribute__((address_space(3))) unsigned int*)l, 16, 0, 0);
}

// ------ fused: router (blocks 0..511, two-level ranks) || W1 transpose -------
// W1T must precede GEMM1; W2T moved into GEMM1's dispatch (R23). Last router
// block (done-counter, device-scope atomics + threadfence, G16) computes
// 256-padded offsets + aux loss inline.
__global__ __launch_bounds__(256) void router_w1t(
    const float* __restrict__ x, const float* __restrict__ Wr,
    const float* __restrict__ W1, unsigned short* __restrict__ W1T,
    unsigned* __restrict__ counts, float* __restrict__ Psum,
    int* __restrict__ tok_e, float* __restrict__ tok_g, int* __restrict__ tok_ls,
    unsigned* __restrict__ done, int* __restrict__ offs, float* __restrict__ aux_out) {
  __shared__ float tile[64][65];
  __shared__ float ps[NE];
  __shared__ unsigned lcnt[NE];
  __shared__ unsigned base[NE];
  const int bid = blockIdx.x;
  const int tid = threadIdx.x;

  if (bid >= 512) {
    // ---- W1 transpose+cvt: (DM x DFF) -> (DFF x DM), 1024 tiles/expert
    const int b = bid - 512;
    const int z = b >> 10;
    const float* I = W1 + (size_t)z * DM * DFF;
    unsigned short* O = W1T + (size_t)z * DM * DFF;
    const int bt = b & 1023;
    const int bx = bt & 63, by = bt >> 6;  // nbx = DFF/64 = 64
    const int r0 = by * 64, c0 = bx * 64;
    const int q = tid & 15, p = tid >> 4;
#pragma unroll
    for (int i = 0; i < 4; ++i) {
      const int r = i * 16 + p;
      const float4 v = *(const float4*)&I[(size_t)(r0 + r) * DFF + c0 + q * 4];
      tile[r][q * 4 + 0] = v.x; tile[r][q * 4 + 1] = v.y;
      tile[r][q * 4 + 2] = v.z; tile[r][q * 4 + 3] = v.w;
    }
    __syncthreads();
#pragma unroll
    for (int i = 0; i < 4; ++i) {
      const int cc = i * 16 + p;
      ushort4 h;
      h.x = f2bf(tile[q * 4 + 0][cc]);
      h.y = f2bf(tile[q * 4 + 1][cc]);
      h.z = f2bf(tile[q * 4 + 2][cc]);
      h.w = f2bf(tile[q * 4 + 3][cc]);
      *(ushort4*)&O[(size_t)(c0 + cc) * DM + r0 + q * 4] = h;
    }
    return;
  }

  // ---- router: two-level ranks (R21-proven, -150us)
  if (tid < NE) { ps[tid] = 0.f; lcnt[tid] = 0u; }
  __syncthreads();
  const int lane = tid & 63, wid = tid >> 6;
  int li0[4], li1[4];
  unsigned lr0[4], lr1[4];
  float lg0[4], lg1[4];
#pragma unroll
  for (int u = 0; u < 4; ++u) {
    const int t = bid * 16 + wid * 4 + u;
    float a[NE];
#pragma unroll
    for (int e = 0; e < NE; ++e) a[e] = 0.f;
#pragma unroll
    for (int i = 0; i < 4; ++i) {
      const int d0 = i * 256 + lane * 4;
      const float4 v = *(const float4*)&x[(size_t)t * DM + d0];
      const float vv[4] = {v.x, v.y, v.z, v.w};
#pragma unroll
      for (int j = 0; j < 4; ++j) {
        const float* wr = &Wr[(size_t)(d0 + j) * NE];
#pragma unroll
        for (int e = 0; e < NE; ++e) a[e] = fmaf(vv[j], wr[e], a[e]);
      }
    }
#pragma unroll
    for (int e = 0; e < NE; ++e)
      for (int s = 32; s > 0; s >>= 1) a[e] += __shfl_xor(a[e], s);
    float mx = a[0];
#pragma unroll
    for (int e = 1; e < NE; ++e) mx = fmaxf(mx, a[e]);
    float p[NE], s = 0.f;
#pragma unroll
    for (int e = 0; e < NE; ++e) { p[e] = expf(a[e] - mx); s += p[e]; }
    float q[NE];
#pragma unroll
    for (int e = 0; e < NE; ++e) q[e] = p[e] / s;
    int i0 = 0; float b0 = q[0];
#pragma unroll
    for (int e = 1; e < NE; ++e) if (q[e] > b0) { b0 = q[e]; i0 = e; }
    int i1 = -1; float b1v = -1.f;
#pragma unroll
    for (int e = 0; e < NE; ++e) if (e != i0 && q[e] > b1v) { b1v = q[e]; i1 = e; }
    const float gs = q[i0] + q[i1];
    li0[u] = i0; li1[u] = i1;
    lg0[u] = q[i0] / gs; lg1[u] = q[i1] / gs;
    if (lane == 0) {
#pragma unroll
      for (int e = 0; e < NE; ++e) atomicAdd(&ps[e], q[e]);
      lr0[u] = atomicAdd(&lcnt[i0], 1u);
      lr1[u] = atomicAdd(&lcnt[i1], 1u);
    }
  }
  __syncthreads();
  if (tid < NE) {
    base[tid] = atomicAdd(&counts[tid], lcnt[tid]);
    atomicAdd(&Psum[tid], ps[tid]);
  }
  __syncthreads();
  if (lane == 0) {
#pragma unroll
    for (int u = 0; u < 4; ++u) {
      const int t = bid * 16 + wid * 4 + u;
      tok_e[2 * t] = li0[u]; tok_e[2 * t + 1] = li1[u];
      tok_g[2 * t] = lg0[u]; tok_g[2 * t + 1] = lg1[u];
      tok_ls[2 * t] = (int)(base[li0[u]] + lr0[u]);
      tok_ls[2 * t + 1] = (int)(base[li1[u]] + lr1[u]);
    }
  }
  __syncthreads();
  if (tid == 0) {
    __threadfence();
    const unsigned d = atomicAdd(done, 1u);
    if (d == 511u) {
      int o = 0; float aux = 0.f;
#pragma unroll
      for (int e = 0; e < NE; ++e) {
        const unsigned c = atomicAdd(&counts[e], 0u);   // atomic read (G16)
        const float pe = atomicAdd(&Psum[e], 0.f);
        offs[e] = o;
        o += (int)((c + (PAD - 1u)) / PAD) * PAD;
        aux += ((float)c / (float)N_TOK) * (pe / (float)N_TOK);
      }
      offs[NE] = o;
      aux_out[0] = 0.01f * (float)NE * aux;
    }
  }
}

// ---------------- gather (compact Xg) ----------------
__global__ __launch_bounds__(256) void gather_kernel(
    const float* __restrict__ x, const int* __restrict__ tok_e,
    const int* __restrict__ tok_ls, const int* __restrict__ offs,
    int* __restrict__ tok_slot, unsigned short* __restrict__ Xg) {
  const int t = blockIdx.x;
  __shared__ int ss[2];
  if (threadIdx.x < 2) {
    const int k = threadIdx.x;
    const int e = tok_e[2 * t + k];
    const int sl = offs[e] + tok_ls[2 * t + k];
    ss[k] = sl;
    tok_slot[2 * t + k] = sl;
  }
  __syncthreads();
  const int i = threadIdx.x;
  const float4 v = ((const float4*)x)[(size_t)t * 256 + i];
  ushort4 h;
  h.x = f2bf(v.x); h.y = f2bf(v.y); h.z = f2bf(v.z); h.w = f2bf(v.w);
  ((ushort4*)Xg)[(size_t)ss[0] * 256 + i] = h;
  ((ushort4*)Xg)[(size_t)ss[1] * 256 + i] = h;
}

// ---------------- shape-templated GEMM, BK=32, ring-3, 2 blocks/CU -----------
// Inner loop FROZEN at R12 best (208us/GEMM, 31% MfmaUtil, 0 conflicts).
// BMODE 0 flat grid: blocks >= NT1 run the W2->W2T transpose hidden under
// GEMM1 (R23-proven win: +2us on the dispatch, -32us serial). Blocks < NT1:
// tn = f%32, gr = f/32. BMODE 1: split-K=2, XCD-banded flat 1152.
// 16B chunks XOR-swizzled ((row>>1)&3) both sides. Per K-tile: 8 ds_read +
// 16 MFMA + 3 stage loads + vmcnt(3) + 1 barrier. tanh-GELU epilogue.
template <int BMODE, bool GELU, typename CT>
__global__ __launch_bounds__(512, 4) void gemmk(
    const unsigned short* __restrict__ Ag, const unsigned short* __restrict__ Bt,
    const float* __restrict__ bias, CT* __restrict__ Cout,
    const int* __restrict__ offs, const int K, const int Nn,
    const size_t c_split_stride,
    const float* __restrict__ TW_in, unsigned short* __restrict__ TW_out) {
  constexpr int BM = (BMODE == 0) ? 256 : 128;
  constexpr int BN = (BMODE == 0) ? 128 : 256;
  constexpr int WN = BN / 64;                  // waves along N
  constexpr int AREG = BM * 32;                // shorts per A ring entry
  constexpr int BREG = BN * 32;                // shorts per B ring entry
  constexpr int SPLIT = (BMODE == 0) ? 1 : 2;

  extern __shared__ unsigned short lds[];
  const int tid = threadIdx.x;

  int tn, gr, ks;
  if (BMODE == 0) {
    const int flat = (int)blockIdx.x;
    if (flat >= NT1) {
      // ---- W2 transpose+cvt (DFF x DM) -> (DM x DFF), 512 threads
      float* tile = (float*)lds;  // [64][65]
      const int b = flat - NT1;
      const int z = b >> 10;
      const float* I = TW_in + (size_t)z * DM * DFF;
      unsigned short* O = TW_out + (size_t)z * DM * DFF;
      const int bt = b & 1023;
      const int bx = bt & 15, by = bt >> 4;  // nbx = DM/64 = 16
      const int r0 = by * 64, c0 = bx * 64;
      const int q = tid & 15, p = tid >> 4;  // p 0..31
#pragma unroll
      for (int i = 0; i < 2; ++i) {
        const int r = i * 32 + p;
        const float4 v = *(const float4*)&I[(size_t)(r0 + r) * DM + c0 + q * 4];
        tile[r * 65 + q * 4 + 0] = v.x; tile[r * 65 + q * 4 + 1] = v.y;
        tile[r * 65 + q * 4 + 2] = v.z; tile[r * 65 + q * 4 + 3] = v.w;
      }
      __syncthreads();
#pragma unroll
      for (int i = 0; i < 2; ++i) {
        const int cc = i * 32 + p;
        ushort4 h;
        h.x = f2bf(tile[(q * 4 + 0) * 65 + cc]);
        h.y = f2bf(tile[(q * 4 + 1) * 65 + cc]);
        h.z = f2bf(tile[(q * 4 + 2) * 65 + cc]);
        h.w = f2bf(tile[(q * 4 + 3) * 65 + cc]);
        *(ushort4*)&O[(size_t)(c0 + cc) * DFF + r0 + q * 4] = h;
      }
      return;
    }
    tn = flat & 31; gr = flat >> 5; ks = 0;   // tn fast
  } else {
    const int flat = (int)blockIdx.x;         // XCD-banded flat
    const int xr = flat & 7;
    const int rest = flat >> 3;
    tn = rest & 3; ks = (rest >> 2) & 1; gr = ((rest >> 3) << 3) + xr;
  }

  const int grow = gr * BM;
  if (grow >= offs[NE]) return;
  int e = 0;
#pragma unroll
  for (int k = 1; k < NE; ++k) if (offs[k] <= grow) e = k;
  const int kext = K / SPLIT;
  const int nt = kext >> 5;  // K-tiles of 32

  const unsigned short* A = Ag + (size_t)grow * K + (size_t)ks * kext;
  const unsigned short* B = Bt + ((size_t)e * Nn + (size_t)tn * BN) * K + (size_t)ks * kext;
  const float* bp = (ks == 0) ? bias : nullptr;
  CT* Cw = Cout + (size_t)ks * c_split_stride;

  unsigned short* LA = lds;                  // 3 x AREG
  unsigned short* LB = lds + 3 * AREG;       // 3 x BREG

  const int lane = tid & 63;
  const int wid = tid >> 6;
  const int wm = wid / WN;
  const int wn = wid % WN;
  const int arow = lane & 15;
  const int kc = lane >> 4;   // 16B chunk 0..3 within 32-short row

  // LDS read addressing: swizzled chunk (kc ^ ((row>>1)&3)); row%8 == arow%8.
  const int sc = ((kc ^ ((arow >> 1) & 3)) << 3);
  const int aBase = (wm * 64 + arow) * 32 + sc;   // + mf*512
  const int bBase = (wn * 64 + arow) * 32 + sc;   // + nf*512

  // stage addressing: chunk c = call*512 + tid; r = c>>2; src chunk
  // (tid&3)^((r>>1)&3) = (tid&3)^((tid>>3)&3) (call adds 128 rows = 0 mod 8).
  const int swzs = (((tid & 3) ^ ((tid >> 3) & 3)) << 3);
  const unsigned short* sA = A + (size_t)(tid >> 2) * K + swzs;
  const unsigned short* sB = B + (size_t)(tid >> 2) * K + swzs;
  const size_t r128 = (size_t)128 * K;
  const size_t dstw = (size_t)wid * 512;  // shorts; lane*16B added by HW

  auto stgA = [&](int db, size_t kt) {
    async16(LA + db * AREG + dstw, sA + kt);
    if constexpr (BMODE == 0) async16(LA + db * AREG + 4096 + dstw, sA + r128 + kt);
  };
  auto stgB = [&](int db, size_t kt) {
    async16(LB + db * BREG + dstw, sB + kt);
    if constexpr (BMODE == 1) async16(LB + db * BREG + 4096 + dstw, sB + r128 + kt);
  };

  f32x4 acc[4][4];
#pragma unroll
  for (int m = 0; m < 4; ++m)
#pragma unroll
    for (int n = 0; n < 4; ++n) acc[m][n] = (f32x4){0.f, 0.f, 0.f, 0.f};

  // prologue: stage T0 -> buf0, T1 -> buf1; wait T0 (counted), barrier.
  stgA(0, 0); stgB(0, 0);
  stgA(1, 32); stgB(1, 32);
  asm volatile("s_waitcnt vmcnt(3)" ::: "memory");
  asm volatile("s_barrier" ::: "memory");

  int d0 = 0;
  for (int T = 0; T < nt; ++T) {
    const int d2 = (d0 >= 1) ? d0 - 1 : d0 + 2;  // (d0+2)%3
    const size_t kt2 = (size_t)((T + 2 < nt) ? T + 2 : 0) << 5;
    const int la = d0 * AREG, lb = d0 * BREG;

    bf16x8 afr[4], bfr[4];
#pragma unroll
    for (int mf = 0; mf < 4; ++mf) afr[mf] = *(const bf16x8*)&LA[la + aBase + mf * 512];
#pragma unroll
    for (int nf = 0; nf < 4; ++nf) bfr[nf] = *(const bf16x8*)&LB[lb + bBase + nf * 512];

    stgA(d2, kt2);
    stgB(d2, kt2);

    __builtin_amdgcn_s_setprio(1);
#pragma unroll
    for (int m = 0; m < 4; ++m)
#pragma unroll
      for (int n = 0; n < 4; ++n)
        acc[m][n] = __builtin_amdgcn_mfma_f32_16x16x32_bf16(afr[m], bfr[n], acc[m][n], 0, 0, 0);
    __builtin_amdgcn_s_setprio(0);

    asm volatile("s_waitcnt vmcnt(3)" ::: "memory");
    asm volatile("s_barrier" ::: "memory");
    d0 = (d0 == 2) ? 0 : d0 + 1;
  }
  asm volatile("s_waitcnt vmcnt(0)" ::: "memory");

  // epilogue: n innermost -> each output line completed back-to-back (no RMW).
  const int rl = (lane >> 4) * 4;
  const int cl = lane & 15;
  float bv[4];
#pragma unroll
  for (int n = 0; n < 4; ++n) {
    const int col = tn * BN + wn * 64 + n * 16 + cl;
    bv[n] = bp ? bp[(size_t)e * Nn + col] : 0.f;
  }
#pragma unroll
  for (int m = 0; m < 4; ++m) {
    const int row = grow + wm * 64 + m * 16 + rl;
#pragma unroll
    for (int jj = 0; jj < 4; ++jj) {
      CT* rowp = Cw + (size_t)(row + jj) * Nn + tn * BN + wn * 64 + cl;
#pragma unroll
      for (int n = 0; n < 4; ++n) {
        float v = acc[m][n][jj] + bv[n];
        if (GELU) {
          // tanh-approx GELU, sigmoid form (inf-safe)
          const float w = -1.5957691216057308f * (v + 0.044715f * v * v * v);
          v = v / (1.f + __expf(w));
        }
        if constexpr (sizeof(CT) == 2) { rowp[n * 16] = (CT)f2bf(v); } else { rowp[n * 16] = (CT)v; }
      }
    }
  }
}

// ---------------- combine: out[t] = g0*(Ya+Yb)[s0] + g1*(Ya+Yb)[s1] ----------
__global__ __launch_bounds__(128) void combine_kernel(
    const unsigned short* __restrict__ Ya, const unsigned short* __restrict__ Yb,
    const int* __restrict__ tok_slot, const float* __restrict__ tok_g,
    float* __restrict__ out) {
  const int t = blockIdx.x;
  const int i = threadIdx.x;
  const int s0 = tok_slot[2 * t], s1 = tok_slot[2 * t + 1];
  const float g0 = tok_g[2 * t], g1 = tok_g[2 * t + 1];
  const u16x8 a0 = ((const u16x8*)Ya)[(size_t)s0 * 128 + i];
  const u16x8 b0 = ((const u16x8*)Yb)[(size_t)s0 * 128 + i];
  const u16x8 a1 = ((const u16x8*)Ya)[(size_t)s1 * 128 + i];
  const u16x8 b1 = ((const u16x8*)Yb)[(size_t)s1 * 128 + i];
  float r[8];
#pragma unroll
  for (int j = 0; j < 8; ++j)
    r[j] = g0 * (bf2f(a0[j]) + bf2f(b0[j])) + g1 * (bf2f(a1[j]) + bf2f(b1[j]));
  float4* op = (float4*)&out[(size_t)t * DM + i * 8];
  op[0] = (float4){r[0], r[1], r[2], r[3]};
  op[1] = (float4){r[4], r[5], r[6], r[7]};
}

extern "C" void kernel_launch(void* const* d_in, const int* in_sizes, int n_in,
                              void* d_out, int out_size, void* d_ws, size_t ws_size,
                              hipStream_t stream) {
  const float* x = (const float*)d_in[0];
  const float* Wr = (const float*)d_in[1];
  const float* W1 = (const float*)d_in[2];
  const float* b1 = (const float*)d_in[3];
  const float* W2 = (const float*)d_in[4];
  const float* b2 = (const float*)d_in[5];
  float* out = (float*)d_out;

  char* w = (char*)d_ws;
  size_t ob = 0;
  auto take = [&](size_t nbytes) -> void* {
    void* p = w + ob;
    ob = (ob + nbytes + 255) & ~(size_t)255;
    return p;
  };
  // Overlap: {W1T,Xg} (dead after GEMM1) share a region with {Ya,Yb} (bf16)
  unsigned short* W2T = (unsigned short*)take((size_t)NE * DM * DFF * 2);   // 64MB
  unsigned short* H = (unsigned short*)take((size_t)CAP * DFF * 2);         // 151MB
  char* R = (char*)take((size_t)NE * DFF * DM * 2 + (size_t)CAP * DM * 2);  // 100MB
  unsigned short* W1T = (unsigned short*)R;                                 // 64MB
  unsigned short* Xg = (unsigned short*)(R + (size_t)NE * DFF * DM * 2);    // 36MB
  unsigned short* Ya = (unsigned short*)R;                                  // 36MB
  unsigned short* Yb = (unsigned short*)(R + (size_t)CAP * DM * 2);         // 36MB
  char* cz = (char*)take(128);  // counts(32) + Psum(32) + done(4), memset-zeroed
  unsigned* counts = (unsigned*)cz;
  float* Psum = (float*)(cz + 32);
  unsigned* done = (unsigned*)(cz + 64);
  int* offs = (int*)take(16 * 4);
  int* tok_e = (int*)take(2 * N_TOK * 4);
  float* tok_g = (float*)take(2 * N_TOK * 4);
  int* tok_ls = (int*)take(2 * N_TOK * 4);
  int* tok_slot = (int*)take(2 * N_TOK * 4);
  (void)ws_size; (void)in_sizes; (void)n_in; (void)out_size;

  hipFuncSetAttribute(reinterpret_cast<const void*>(&gemmk<0, true, unsigned short>),
                      hipFuncAttributeMaxDynamicSharedMemorySize, 73728);
  hipFuncSetAttribute(reinterpret_cast<const void*>(&gemmk<1, false, unsigned short>),
                      hipFuncAttributeMaxDynamicSharedMemorySize, 73728);

  hipMemsetAsync(cz, 0, 128, stream);
  // fused router || W1 transpose (+inline offsets via done-counter)
  router_w1t<<<512 + 8 * 1024, 256, 0, stream>>>(
      x, Wr, W1, W1T, counts, Psum, tok_e, tok_g, tok_ls,
      done, offs, out + (size_t)N_TOK * DM);
  gather_kernel<<<N_TOK, 256, 0, stream>>>(x, tok_e, tok_ls, offs, tok_slot, Xg);
  // GEMM1 (BM=256,BN=128) + fused W2 transpose (blocks >= NT1, hidden tail)
  gemmk<0, true, unsigned short><<<dim3(NT1 + 8 * 1024), 512, 73728, stream>>>(
      Xg, W1T, b1, H, offs, DM, DFF, 0, W2, W2T);
  // GEMM2 (BM=128,BN=256, split-K=2): XCD-banded flat 1152; halves write Ya/Yb
  gemmk<1, false, unsigned short><<<dim3((CAP / 128) * 8), 512, 73728, stream>>>(
      H, W2T, b2, Ya, offs, DFF, DM, (size_t)CAP * DM, nullptr, nullptr);
  combine_kernel<<<N_TOK, 128, 0, stream>>>(Ya, Yb, tok_slot, tok_g, out);
}